// Round 13
// baseline (321.646 us; speedup 1.0000x reference)
//
#include <hip/hip_runtime.h>
#include <cstdint>
#include <cstddef>

typedef __bf16 bf16x8 __attribute__((ext_vector_type(8)));
typedef float f32x4 __attribute__((ext_vector_type(4)));
using u16 = unsigned short;
using u32 = unsigned int;

// ---------- helpers ----------
__device__ __forceinline__ u16 f2b(float f) {
  u32 u = __float_as_uint(f);
  u32 r = u + 0x7FFFu + ((u >> 16) & 1u);
  return (u16)(r >> 16);
}
__device__ __forceinline__ float b2f(u16 h) { return __uint_as_float((u32)h << 16); }

__device__ __forceinline__ void gload16(const void* g, void* l) {
  __builtin_amdgcn_global_load_lds((const __attribute__((address_space(1))) void*)g,
                                   (__attribute__((address_space(3))) void*)l, 16, 0, 0);
}

__device__ __forceinline__ u32 mapf(float f) {
  u32 u = __float_as_uint(f);
  return (u & 0x80000000u) ? ~u : (u | 0x80000000u);
}
__device__ __forceinline__ float unmapf(u32 k) {
  u32 u = (k & 0x80000000u) ? (k ^ 0x80000000u) : ~k;
  return __uint_as_float(u);
}
__device__ __forceinline__ u32 cvtpk(float lo, float hi) {
  u32 r;
  asm("v_cvt_pk_bf16_f32 %0, %1, %2" : "=v"(r) : "v"(lo), "v"(hi));
  return r;
}

#define MFMA __builtin_amdgcn_mfma_f32_16x16x32_bf16

// ---------- positional encoding ----------
__global__ void pe_kernel(float* __restrict__ pe) {
  int i = blockIdx.x * 256 + threadIdx.x;
  if (i >= 512 * 512) return;
  int t = i >> 9, d = i & 511;
  double ang = (double)t * exp((double)d * (-2.0 / 512.0) * log(10000.0));
  double v = (d & 1) ? cos(ang) : sin(ang);
  pe[i] = (float)(v * 22.627416997969522);
}

// ---------- tiled transpose + bf16(-split) convert: in[R][C] f32 -> out[C][R] u16 ----------
template <int SPLIT>
__global__ __launch_bounds__(256) void tconv_kernel(const float* __restrict__ in, int R, int C,
                                                    u16* __restrict__ outh,
                                                    u16* __restrict__ outl) {
  __shared__ float tile[64][65];
  const int t = threadIdx.x;
  const long r0 = (long)blockIdx.x * 64, c0 = (long)blockIdx.y * 64;
#pragma unroll
  for (int it = 0; it < 4; ++it) {
    int r = it * 16 + (t >> 4);
    int c = (t & 15) * 4;
    float4 v = *(const float4*)&in[(r0 + r) * C + c0 + c];
    tile[r][c] = v.x;
    tile[r][c + 1] = v.y;
    tile[r][c + 2] = v.z;
    tile[r][c + 3] = v.w;
  }
  __syncthreads();
#pragma unroll
  for (int it = 0; it < 4; ++it) {
    int oc = it * 16 + (t >> 4);  // input col = output row
    int orr = (t & 15) * 4;       // input row = output col
    ushort4 h4, l4;
    u16* hp = (u16*)&h4;
    u16* lp = (u16*)&l4;
#pragma unroll
    for (int j = 0; j < 4; ++j) {
      float v = tile[orr + j][oc];
      u16 h = f2b(v);
      hp[j] = h;
      if (SPLIT) lp[j] = f2b(v - b2f(h));
    }
    *(ushort4*)&outh[(c0 + oc) * R + r0 + orr] = h4;
    if (SPLIT) *(ushort4*)&outl[(c0 + oc) * R + r0 + orr] = l4;
  }
}

// ---------- straight f32 -> bf16 convert (vectorized) ----------
__global__ void conv_kernel(const float* __restrict__ in, u16* __restrict__ out, int n4) {
  int i4 = blockIdx.x * 256 + threadIdx.x;
  if (i4 >= n4) return;
  float4 v = *(const float4*)&in[i4 * 4];
  ushort4 o = {f2b(v.x), f2b(v.y), f2b(v.z), f2b(v.w)};
  *(ushort4*)&out[i4 * 4] = o;
}

// ---------- q1/k1 (split bf16), vectorized x4 ----------
__global__ void prep_kernel(const float* __restrict__ q, const float* __restrict__ pe,
                            u16* __restrict__ q1h, u16* __restrict__ q1l,
                            u16* __restrict__ k1h, u16* __restrict__ k1l) {
  int i4 = blockIdx.x * 256 + threadIdx.x;
  if (i4 >= 2097152) return;
  int i = i4 * 4;
  int td = i & (262144 - 1);
  float4 qv = *(const float4*)&q[i];
  float4 pv = *(const float4*)&pe[td];
  float q1[4] = {qv.x + pv.x, qv.y + pv.y, qv.z + pv.z, qv.w + pv.w};
  float pp[4] = {pv.x, pv.y, pv.z, pv.w};
  ushort4 qh4, ql4, kh4, kl4;
  u16* qhp = (u16*)&qh4;
  u16* qlp = (u16*)&ql4;
  u16* khp = (u16*)&kh4;
  u16* klp = (u16*)&kl4;
#pragma unroll
  for (int j = 0; j < 4; ++j) {
    float k1 = q1[j] + pp[j];
    u16 h = f2b(q1[j]);
    qhp[j] = h;
    qlp[j] = f2b(q1[j] - b2f(h));
    h = f2b(k1);
    khp[j] = h;
    klp[j] = f2b(k1 - b2f(h));
  }
  *(ushort4*)&q1h[i] = qh4;
  *(ushort4*)&q1l[i] = ql4;
  *(ushort4*)&k1h[i] = kh4;
  *(ushort4*)&k1l[i] = kl4;
}

// ---------- generic GEMM: C[M,N] = A[M,K] * B^T ----------
#define GM_BF16 0
#define GM_RELU 2
#define GM_ADDF32 3

template <int MODE>
__global__ __launch_bounds__(256, 3) void gemm_bt(const u16* __restrict__ A,
                                                  const u16* __restrict__ B, int M, int N, int K,
                                                  u16* __restrict__ outb, float* __restrict__ outf,
                                                  const float* __restrict__ res) {
  __shared__ u16 As[128 * 32];
  __shared__ u16 Bs[128 * 32];
  const int tid = threadIdx.x, lane = tid & 63, w = tid >> 6;
  const int wm = w >> 1, wn = w & 1;
  const long aBase = (long)blockIdx.x * 128;
  const long bBase = (long)blockIdx.y * 128;
  f32x4 acc[4][4] = {};
  const int nk = K >> 5;
  for (int kt = 0; kt < nk; ++kt) {
#pragma unroll
    for (int i = 0; i < 2; ++i) {
      const int c = w * 2 + i;
      const int off = c * 1024 + lane * 16;
      const int r = off >> 6, cb = off & 63;
      gload16((const char*)A + ((aBase + r) * (long)K + (long)kt * 32) * 2 + cb,
              (char*)As + c * 1024);
      gload16((const char*)B + ((bBase + r) * (long)K + (long)kt * 32) * 2 + cb,
              (char*)Bs + c * 1024);
    }
    __syncthreads();
    bf16x8 af[4], bfr[4];
#pragma unroll
    for (int x = 0; x < 4; ++x) {
      af[x] = *(const bf16x8*)&As[(wm * 64 + x * 16 + (lane & 15)) * 32 + (lane >> 4) * 8];
      bfr[x] = *(const bf16x8*)&Bs[(wn * 64 + x * 16 + (lane & 15)) * 32 + (lane >> 4) * 8];
    }
#pragma unroll
    for (int mf = 0; mf < 4; ++mf)
#pragma unroll
      for (int nf = 0; nf < 4; ++nf)
        acc[mf][nf] = MFMA(af[mf], bfr[nf], acc[mf][nf], 0, 0, 0);
    __syncthreads();
  }
#pragma unroll
  for (int mf = 0; mf < 4; ++mf)
#pragma unroll
    for (int nf = 0; nf < 4; ++nf) {
      const long row0 = aBase + wm * 64 + mf * 16 + (lane >> 4) * 4;
      const long col = bBase + wn * 64 + nf * 16 + (lane & 15);
#pragma unroll
      for (int j = 0; j < 4; ++j) {
        float v = acc[mf][nf][j];
        const long row = row0 + j;
        if constexpr (MODE == GM_BF16)
          outb[row * N + col] = f2b(v);
        else if constexpr (MODE == GM_RELU)
          outb[row * N + col] = f2b(v > 0.f ? v : 0.f);
        else
          outf[row * N + col] = res[row * N + col] + v;
      }
    }
}

// ---------- split-precision GEMM ----------
__global__ __launch_bounds__(256, 3) void gemm_split(const u16* __restrict__ Ah,
                                                     const u16* __restrict__ Al,
                                                     const u16* __restrict__ Bh,
                                                     const u16* __restrict__ Bl, int M, int N,
                                                     int K, u16* __restrict__ Oh,
                                                     u16* __restrict__ Ol) {
  __shared__ u16 Ash[4096], Asl[4096], Bsh[4096], Bsl[4096];
  const int tid = threadIdx.x, lane = tid & 63, w = tid >> 6;
  const int wm = w >> 1, wn = w & 1;
  const long aBase = (long)blockIdx.x * 128;
  const long bBase = (long)blockIdx.y * 128;
  f32x4 acc[4][4] = {};
  const int nk = K >> 5;
  for (int kt = 0; kt < nk; ++kt) {
#pragma unroll
    for (int i = 0; i < 2; ++i) {
      const int c = w * 2 + i;
      const int off = c * 1024 + lane * 16;
      const int r = off >> 6, cb = off & 63;
      long ga = ((aBase + r) * (long)K + (long)kt * 32) * 2 + cb;
      long gb = ((bBase + r) * (long)K + (long)kt * 32) * 2 + cb;
      gload16((const char*)Ah + ga, (char*)Ash + c * 1024);
      gload16((const char*)Al + ga, (char*)Asl + c * 1024);
      gload16((const char*)Bh + gb, (char*)Bsh + c * 1024);
      gload16((const char*)Bl + gb, (char*)Bsl + c * 1024);
    }
    __syncthreads();
    bf16x8 ah[4], al[4], bh[4], bl[4];
#pragma unroll
    for (int x = 0; x < 4; ++x) {
      int ao = (wm * 64 + x * 16 + (lane & 15)) * 32 + (lane >> 4) * 8;
      int bo = (wn * 64 + x * 16 + (lane & 15)) * 32 + (lane >> 4) * 8;
      ah[x] = *(const bf16x8*)&Ash[ao];
      al[x] = *(const bf16x8*)&Asl[ao];
      bh[x] = *(const bf16x8*)&Bsh[bo];
      bl[x] = *(const bf16x8*)&Bsl[bo];
    }
#pragma unroll
    for (int mf = 0; mf < 4; ++mf)
#pragma unroll
      for (int nf = 0; nf < 4; ++nf) {
        acc[mf][nf] = MFMA(ah[mf], bh[nf], acc[mf][nf], 0, 0, 0);
        acc[mf][nf] = MFMA(ah[mf], bl[nf], acc[mf][nf], 0, 0, 0);
        acc[mf][nf] = MFMA(al[mf], bh[nf], acc[mf][nf], 0, 0, 0);
      }
    __syncthreads();
  }
#pragma unroll
  for (int mf = 0; mf < 4; ++mf)
#pragma unroll
    for (int nf = 0; nf < 4; ++nf) {
      const long row0 = aBase + wm * 64 + mf * 16 + (lane >> 4) * 4;
      const long col = bBase + wn * 64 + nf * 16 + (lane & 15);
#pragma unroll
      for (int j = 0; j < 4; ++j) {
        float v = acc[mf][nf][j];
        const long row = row0 + j;
        u16 h = f2b(v);
        Oh[row * N + col] = h;
        Ol[row * N + col] = f2b(v - b2f(h));
      }
    }
}

// ---------- fused attention: one block per (h,b), 8 waves, K panel LDS-resident ----------
// Phase 1: colmax over q (LDS atomicMax), same as round 9.
// Phase 2: ONE K-sweep with all 4 q-subtiles (states) — each K-fragment LDS read and each
// V global fetch is shared by 4 states (was 2); per-state math identical to round 9.
__global__ __launch_bounds__(512, 2) void attn_fused(
    const u16* __restrict__ Qh, const u16* __restrict__ Ql, const u16* __restrict__ Kh,
    const u16* __restrict__ Kl, const u16* __restrict__ Vt, const int* __restrict__ qmask,
    const u16* __restrict__ r1h, const u16* __restrict__ r1l, float* __restrict__ resf,
    u16* __restrict__ resb) {
  extern __shared__ char smem[];
  u16* Khi = (u16*)smem;              // 8 chunks x [64][64] u16, swizzled (64 KB)
  u16* Klo = (u16*)(smem + 65536);    // 64 KB
  u32* mloc = (u32*)(smem + 131072);  // 512 x u32 (2 KB); later reused as float mks
  float* mksf = (float*)(smem + 131072);
  const int tid = threadIdx.x, lane = tid & 63, w = tid >> 6;
  const int qll = lane & 15, g = lane >> 4;
  const int hb = blockIdx.x, b = hb >> 3, h = hb & 7;
  const int qm = qmask[b];
  mloc[tid] = 0u;  // mapped sentinel below all mapped reals
  const int srccb = 16 * ((lane & 7) ^ ((lane >> 3) & 7));
  // stage full K panel (hi+lo), 8 chunks of 64 rows; linear LDS dest + inverse-swizzled source
#pragma unroll
  for (int c = 0; c < 8; ++c) {
    long gb = ((long)(b * 512 + c * 64 + w * 8 + (lane >> 3)) * 512 + h * 64) * 2 + srccb;
    gload16((const char*)Kh + gb, (char*)Khi + c * 8192 + w * 1024);
    gload16((const char*)Kl + gb, (char*)Klo + c * 8192 + w * 1024);
  }
  // Q fragments, all 4 subtiles of this wave (used in BOTH phases)
  bf16x8 qfh[4][2], qfl[4][2];
#pragma unroll
  for (int s = 0; s < 4; ++s) {
    const long qr = (long)(b * 512 + w * 64 + s * 16 + qll) * 512 + h * 64 + g * 8;
    qfh[s][0] = *(const bf16x8*)&Qh[qr];
    qfh[s][1] = *(const bf16x8*)&Qh[qr + 32];
    qfl[s][0] = *(const bf16x8*)&Ql[qr];
    qfl[s][1] = *(const bf16x8*)&Ql[qr + 32];
  }
  __syncthreads();  // K staged, mloc zeros visible
  const int sw0 = 8 * (g ^ (qll & 7));
  const int sw1 = 8 * ((4 + g) ^ (qll & 7));
  // ---- phase 1: column max over q ----
  for (int kc = 0; kc < 8; ++kc) {
    const int cb = kc * 4096;
    __builtin_amdgcn_s_setprio(1);
#pragma unroll
    for (int kt = 0; kt < 4; ++kt) {
      const int ko = cb + (kt * 16 + qll) * 64;
      bf16x8 kh0 = *(const bf16x8*)&Khi[ko + sw0];
      bf16x8 kl0 = *(const bf16x8*)&Klo[ko + sw0];
      bf16x8 kh1 = *(const bf16x8*)&Khi[ko + sw1];
      bf16x8 kl1 = *(const bf16x8*)&Klo[ko + sw1];
      float vmax = -3.0e38f;
#pragma unroll
      for (int s = 0; s < 4; ++s) {
        f32x4 acc = {0.f, 0.f, 0.f, 0.f};
        acc = MFMA(qfh[s][0], kh0, acc, 0, 0, 0);
        acc = MFMA(qfh[s][0], kl0, acc, 0, 0, 0);
        acc = MFMA(qfl[s][0], kh0, acc, 0, 0, 0);
        acc = MFMA(qfh[s][1], kh1, acc, 0, 0, 0);
        acc = MFMA(qfh[s][1], kl1, acc, 0, 0, 0);
        acc = MFMA(qfl[s][1], kh1, acc, 0, 0, 0);
        vmax = fmaxf(vmax, fmaxf(fmaxf(acc[0], acc[1]), fmaxf(acc[2], acc[3])));
      }
      vmax = fmaxf(vmax, __shfl_xor(vmax, 16));
      vmax = fmaxf(vmax, __shfl_xor(vmax, 32));
      if (lane < 16) atomicMax(&mloc[kc * 64 + kt * 16 + qll], mapf(vmax));
    }
    __builtin_amdgcn_s_setprio(0);
  }
  __syncthreads();
  float mv = 0.125f * unmapf(mloc[tid]);
  __syncthreads();
  mksf[tid] = mv;
  __syncthreads();
  // ---- phase 2: single K sweep, 4 states ----
  const u16* vb = Vt + (long)(h * 64) * 16384 + b * 512;
  const int src0 = (g & 1) * 32 + qll;
  const int src1 = src0 + 16;
  const bool lowh = g < 2;
  f32x4 o[4][4] = {};
  float mr[4] = {-3.0e38f, -3.0e38f, -3.0e38f, -3.0e38f};
  float rsum[4] = {0.f, 0.f, 0.f, 0.f};
  for (int kc = 0; kc < 8; ++kc) {
    // V fragments for this chunk (shared by all 4 states)
    bf16x8 vf[2][4];
#pragma unroll
    for (int k2 = 0; k2 < 2; ++k2)
#pragma unroll
      for (int nf = 0; nf < 4; ++nf)
        vf[k2][nf] =
            *(const bf16x8*)&vb[(long)(nf * 16 + qll) * 16384 + (kc * 2 + k2) * 32 + g * 8];
    // S^T tiles for all 4 states; K frags read ONCE per kt
    const int cb = kc * 4096;
    f32x4 s4[4][4] = {};  // [state][kt]
    __builtin_amdgcn_s_setprio(1);
#pragma unroll
    for (int kt = 0; kt < 4; ++kt) {
      const int ko = cb + (kt * 16 + qll) * 64;
      bf16x8 kh0 = *(const bf16x8*)&Khi[ko + sw0];
      bf16x8 kl0 = *(const bf16x8*)&Klo[ko + sw0];
      bf16x8 kh1 = *(const bf16x8*)&Khi[ko + sw1];
      bf16x8 kl1 = *(const bf16x8*)&Klo[ko + sw1];
#pragma unroll
      for (int s = 0; s < 4; ++s) {
        s4[s][kt] = MFMA(kh0, qfh[s][0], s4[s][kt], 0, 0, 0);
        s4[s][kt] = MFMA(kh0, qfl[s][0], s4[s][kt], 0, 0, 0);
        s4[s][kt] = MFMA(kl0, qfh[s][0], s4[s][kt], 0, 0, 0);
        s4[s][kt] = MFMA(kh1, qfh[s][1], s4[s][kt], 0, 0, 0);
        s4[s][kt] = MFMA(kh1, qfl[s][1], s4[s][kt], 0, 0, 0);
        s4[s][kt] = MFMA(kl1, qfh[s][1], s4[s][kt], 0, 0, 0);
      }
    }
    __builtin_amdgcn_s_setprio(0);
    // per state: z, running max, rescale, exp, pack, PV (identical math to round 9)
#pragma unroll
    for (int s = 0; s < 4; ++s) {
      float pm = mr[s];
#pragma unroll
      for (int kt = 0; kt < 4; ++kt) {
        f32x4 mrow = *(const f32x4*)&mksf[kc * 64 + kt * 16 + g * 4];
#pragma unroll
        for (int j = 0; j < 4; ++j) {
          float z = s4[s][kt][j] * 0.125f - mrow[j];
          s4[s][kt][j] = z;
          pm = fmaxf(pm, z);
        }
      }
      pm = fmaxf(pm, __shfl_xor(pm, 16));
      pm = fmaxf(pm, __shfl_xor(pm, 32));
      const float f = __expf(mr[s] - pm);
      mr[s] = pm;
      rsum[s] *= f;
#pragma unroll
      for (int nf = 0; nf < 4; ++nf) {
        o[s][nf][0] *= f;
        o[s][nf][1] *= f;
        o[s][nf][2] *= f;
        o[s][nf][3] *= f;
      }
      u32 pk0[4], pk1[4];
#pragma unroll
      for (int kt = 0; kt < 4; ++kt) {
        float p0 = __expf(s4[s][kt][0] - pm);
        float p1 = __expf(s4[s][kt][1] - pm);
        float p2 = __expf(s4[s][kt][2] - pm);
        float p3 = __expf(s4[s][kt][3] - pm);
        rsum[s] += (p0 + p1) + (p2 + p3);
        pk0[kt] = cvtpk(p0, p1);
        pk1[kt] = cvtpk(p2, p3);
      }
      __builtin_amdgcn_s_setprio(1);
#pragma unroll
      for (int k2 = 0; k2 < 2; ++k2) {
        const int fA = 2 * k2, fB = 2 * k2 + 1;
        u32 a00 = __shfl(pk0[fA], src0), b00 = __shfl(pk0[fB], src0);
        u32 a10 = __shfl(pk1[fA], src0), b10 = __shfl(pk1[fB], src0);
        u32 a01 = __shfl(pk0[fA], src1), b01 = __shfl(pk0[fB], src1);
        u32 a11 = __shfl(pk1[fA], src1), b11 = __shfl(pk1[fB], src1);
        union {
          u32 u[4];
          bf16x8 v;
        } pf;
        pf.u[0] = lowh ? a00 : b00;
        pf.u[1] = lowh ? a10 : b10;
        pf.u[2] = lowh ? a01 : b01;
        pf.u[3] = lowh ? a11 : b11;
#pragma unroll
        for (int nf = 0; nf < 4; ++nf) o[s][nf] = MFMA(vf[k2][nf], pf.v, o[s][nf], 0, 0, 0);
      }
      __builtin_amdgcn_s_setprio(0);
    }
  }
  // epilogue: all 4 states
#pragma unroll
  for (int s = 0; s < 4; ++s) {
    rsum[s] += __shfl_xor(rsum[s], 16);
    rsum[s] += __shfl_xor(rsum[s], 32);
    const int qg = w * 64 + s * 16 + qll;
    const float sc = (qg < qm) ? (1.0f / rsum[s]) : 0.0f;
#pragma unroll
    for (int nf = 0; nf < 4; ++nf) {
      const int col = h * 64 + nf * 16 + g * 4;
      const long idx = (long)(b * 512 + qg) * 512 + col;
      ushort4 qh4 = *(const ushort4*)&r1h[idx];
      ushort4 ql4 = *(const ushort4*)&r1l[idx];
      float v0 = o[s][nf][0] * sc + b2f(qh4.x) + b2f(ql4.x);
      float v1 = o[s][nf][1] * sc + b2f(qh4.y) + b2f(ql4.y);
      float v2 = o[s][nf][2] * sc + b2f(qh4.z) + b2f(ql4.z);
      float v3 = o[s][nf][3] * sc + b2f(qh4.w) + b2f(ql4.w);
      *(float4*)&resf[idx] = make_float4(v0, v1, v2, v3);
      ushort4 rb = {f2b(v0), f2b(v1), f2b(v2), f2b(v3)};
      *(ushort4*)&resb[idx] = rb;
    }
  }
}

// ---------- launch ----------
extern "C" void kernel_launch(void* const* d_in, const int* in_sizes, int n_in, void* d_out,
                              int out_size, void* d_ws, size_t ws_size, hipStream_t stream) {
  (void)in_sizes;
  (void)n_in;
  (void)out_size;
  (void)ws_size;
  const float* queries = (const float*)d_in[0];
  const int* qmask = (const int*)d_in[2];
  const float* WQ = (const float*)d_in[4];
  const float* WK = (const float*)d_in[5];
  const float* WV = (const float*)d_in[6];
  const float* f1 = (const float*)d_in[7];
  const float* f2 = (const float*)d_in[8];
  float* out = (float*)d_out;
  char* ws = (char*)d_ws;
  const size_t A = 16777216;
  u16* q1h = (u16*)(ws + 0 * A);
  u16* q1l = (u16*)(ws + 1 * A);
  u16* k1h = (u16*)(ws + 2 * A);
  u16* k1l = (u16*)(ws + 3 * A);
  u16* Qh = (u16*)(ws + 4 * A);
  u16* Ql = (u16*)(ws + 5 * A);
  u16* Kh = (u16*)(ws + 6 * A);
  u16* Kl = (u16*)(ws + 7 * A);
  u16* Vt = (u16*)(ws + 8 * A);
  u16* resb = (u16*)(ws + 9 * A);
  // hid (64 MiB) aliases slots 0-3; q1h/q1l last read by attn_fused (stream-ordered before FFN1)
  u16* hid = (u16*)(ws + 0 * A);
  float* pe = (float*)(ws + 10 * A);
  char* wbase = ws + 10 * A + 1572864;
  u16* WQth = (u16*)(wbase + 0 * 524288);
  u16* WQtl = (u16*)(wbase + 1 * 524288);
  u16* WKth = (u16*)(wbase + 2 * 524288);
  u16* WKtl = (u16*)(wbase + 3 * 524288);
  u16* WKb = (u16*)(wbase + 4 * 524288);
  u16* WVt_w = (u16*)(wbase + 5 * 524288);
  u16* WKVt = (u16*)(wbase + 6 * 524288);
  u16* f1t = (u16*)(wbase + 7 * 524288);
  u16* f2t = (u16*)(wbase + 7 * 524288 + 2097152);

  pe_kernel<<<1024, 256, 0, stream>>>(pe);
  // weight conversions: tiled transposes (coalesced) + straight converts
  tconv_kernel<1><<<dim3(8, 8), 256, 0, stream>>>(WQ, 512, 512, WQth, WQtl);
  tconv_kernel<1><<<dim3(8, 8), 256, 0, stream>>>(WK, 512, 512, WKth, WKtl);
  tconv_kernel<0><<<dim3(8, 8), 256, 0, stream>>>(WV, 512, 512, WVt_w, nullptr);
  tconv_kernel<0><<<dim3(8, 32), 256, 0, stream>>>(f1, 512, 2048, f1t, nullptr);
  tconv_kernel<0><<<dim3(32, 8), 256, 0, stream>>>(f2, 2048, 512, f2t, nullptr);
  conv_kernel<<<256, 256, 0, stream>>>(WK, WKb, 65536);
  prep_kernel<<<8192, 256, 0, stream>>>(queries, pe, q1h, q1l, k1h, k1l);
  // WKVt[v][n] = (WK@WV)^T : C = WVt_w * WKb^T
  gemm_bt<GM_BF16><<<dim3(4, 4), 256, 0, stream>>>(WVt_w, WKb, 512, 512, 512, WKVt, nullptr,
                                                   nullptr);
  gemm_split<<<dim3(128, 4), 256, 0, stream>>>(q1h, q1l, WQth, WQtl, 16384, 512, 512, Qh, Ql);
  gemm_split<<<dim3(128, 4), 256, 0, stream>>>(k1h, k1l, WKth, WKtl, 16384, 512, 512, Kh, Kl);
  // Vt[v][m] = V^T directly: C = WKVt * k1h^T
  gemm_bt<GM_BF16><<<dim3(4, 128), 256, 0, stream>>>(WKVt, k1h, 512, 16384, 512, Vt, nullptr,
                                                     nullptr);
  hipFuncSetAttribute((const void*)attn_fused, hipFuncAttributeMaxDynamicSharedMemorySize, 133120);
  attn_fused<<<256, 512, 133120, stream>>>(Qh, Ql, Kh, Kl, Vt, qmask, q1h, q1l, out, resb);
  gemm_bt<GM_RELU><<<dim3(128, 16), 256, 0, stream>>>(resb, f1t, 16384, 2048, 512, hid, nullptr,
                                                      nullptr);
  gemm_bt<GM_ADDF32><<<dim3(128, 4), 256, 0, stream>>>(hid, f2t, 16384, 512, 2048, nullptr, out,
                                                       out);
}

// Round 14
// 310.647 us; speedup vs baseline: 1.0354x; 1.0354x over previous
//
#include <hip/hip_runtime.h>
#include <cstdint>
#include <cstddef>

typedef __bf16 bf16x8 __attribute__((ext_vector_type(8)));
typedef float f32x4 __attribute__((ext_vector_type(4)));
using u16 = unsigned short;
using u32 = unsigned int;

// ---------- helpers ----------
__device__ __forceinline__ u16 f2b(float f) {
  u32 u = __float_as_uint(f);
  u32 r = u + 0x7FFFu + ((u >> 16) & 1u);
  return (u16)(r >> 16);
}
__device__ __forceinline__ float b2f(u16 h) { return __uint_as_float((u32)h << 16); }

__device__ __forceinline__ void gload16(const void* g, void* l) {
  __builtin_amdgcn_global_load_lds((const __attribute__((address_space(1))) void*)g,
                                   (__attribute__((address_space(3))) void*)l, 16, 0, 0);
}

__device__ __forceinline__ u32 mapf(float f) {
  u32 u = __float_as_uint(f);
  return (u & 0x80000000u) ? ~u : (u | 0x80000000u);
}
__device__ __forceinline__ float unmapf(u32 k) {
  u32 u = (k & 0x80000000u) ? (k ^ 0x80000000u) : ~k;
  return __uint_as_float(u);
}
__device__ __forceinline__ u32 cvtpk(float lo, float hi) {
  u32 r;
  asm("v_cvt_pk_bf16_f32 %0, %1, %2" : "=v"(r) : "v"(lo), "v"(hi));
  return r;
}

#define MFMA __builtin_amdgcn_mfma_f32_16x16x32_bf16

// ---------- positional encoding ----------
__global__ void pe_kernel(float* __restrict__ pe) {
  int i = blockIdx.x * 256 + threadIdx.x;
  if (i >= 512 * 512) return;
  int t = i >> 9, d = i & 511;
  double ang = (double)t * exp((double)d * (-2.0 / 512.0) * log(10000.0));
  double v = (d & 1) ? cos(ang) : sin(ang);
  pe[i] = (float)(v * 22.627416997969522);
}

// ---------- merged weight prep: 5 tiled transposes + 1 elementwise convert ----------
// blocks [0,64):WQ split-T, [64,128):WK split-T, [128,192):WV T, [192,448):f1 T,
// [448,704):f2 T, [704,960): WK->WKb elementwise. Bit-identical to the former kernels.
__global__ __launch_bounds__(256) void wprep_kernel(
    const float* __restrict__ WQ, const float* __restrict__ WK, const float* __restrict__ WV,
    const float* __restrict__ f1, const float* __restrict__ f2, u16* __restrict__ WQth,
    u16* __restrict__ WQtl, u16* __restrict__ WKth, u16* __restrict__ WKtl,
    u16* __restrict__ WVt, u16* __restrict__ f1t, u16* __restrict__ f2t,
    u16* __restrict__ WKb) {
  __shared__ float tile[64][65];
  const int bid = blockIdx.x, t = threadIdx.x;
  if (bid >= 704) {  // elementwise WK -> bf16
    int i4 = (bid - 704) * 256 + t;
    float4 v = *(const float4*)&WK[i4 * 4];
    ushort4 o = {f2b(v.x), f2b(v.y), f2b(v.z), f2b(v.w)};
    *(ushort4*)&WKb[i4 * 4] = o;
    return;
  }
  const float* in;
  int R, C, bx, by;
  u16 *oh, *ol;
  bool split;
  if (bid < 64) {
    in = WQ; R = 512; C = 512; oh = WQth; ol = WQtl; split = true; bx = bid % 8; by = bid / 8;
  } else if (bid < 128) {
    int l = bid - 64;
    in = WK; R = 512; C = 512; oh = WKth; ol = WKtl; split = true; bx = l % 8; by = l / 8;
  } else if (bid < 192) {
    int l = bid - 128;
    in = WV; R = 512; C = 512; oh = WVt; ol = nullptr; split = false; bx = l % 8; by = l / 8;
  } else if (bid < 448) {
    int l = bid - 192;
    in = f1; R = 512; C = 2048; oh = f1t; ol = nullptr; split = false; bx = l % 8; by = l / 8;
  } else {
    int l = bid - 448;
    in = f2; R = 2048; C = 512; oh = f2t; ol = nullptr; split = false; bx = l % 32; by = l / 32;
  }
  const long r0 = (long)bx * 64, c0 = (long)by * 64;
#pragma unroll
  for (int it = 0; it < 4; ++it) {
    int r = it * 16 + (t >> 4);
    int c = (t & 15) * 4;
    float4 v = *(const float4*)&in[(r0 + r) * C + c0 + c];
    tile[r][c] = v.x;
    tile[r][c + 1] = v.y;
    tile[r][c + 2] = v.z;
    tile[r][c + 3] = v.w;
  }
  __syncthreads();
#pragma unroll
  for (int it = 0; it < 4; ++it) {
    int oc = it * 16 + (t >> 4);  // input col = output row
    int orr = (t & 15) * 4;       // input row = output col
    ushort4 h4, l4;
    u16* hp = (u16*)&h4;
    u16* lp = (u16*)&l4;
#pragma unroll
    for (int j = 0; j < 4; ++j) {
      float v = tile[orr + j][oc];
      u16 h = f2b(v);
      hp[j] = h;
      if (split) lp[j] = f2b(v - b2f(h));
    }
    *(ushort4*)&oh[(c0 + oc) * R + r0 + orr] = h4;
    if (split) *(ushort4*)&ol[(c0 + oc) * R + r0 + orr] = l4;
  }
}

// ---------- q1/k1 (split bf16), vectorized x4 ----------
__global__ void prep_kernel(const float* __restrict__ q, const float* __restrict__ pe,
                            u16* __restrict__ q1h, u16* __restrict__ q1l,
                            u16* __restrict__ k1h, u16* __restrict__ k1l) {
  int i4 = blockIdx.x * 256 + threadIdx.x;
  if (i4 >= 2097152) return;
  int i = i4 * 4;
  int td = i & (262144 - 1);
  float4 qv = *(const float4*)&q[i];
  float4 pv = *(const float4*)&pe[td];
  float q1[4] = {qv.x + pv.x, qv.y + pv.y, qv.z + pv.z, qv.w + pv.w};
  float pp[4] = {pv.x, pv.y, pv.z, pv.w};
  ushort4 qh4, ql4, kh4, kl4;
  u16* qhp = (u16*)&qh4;
  u16* qlp = (u16*)&ql4;
  u16* khp = (u16*)&kh4;
  u16* klp = (u16*)&kl4;
#pragma unroll
  for (int j = 0; j < 4; ++j) {
    float k1 = q1[j] + pp[j];
    u16 h = f2b(q1[j]);
    qhp[j] = h;
    qlp[j] = f2b(q1[j] - b2f(h));
    h = f2b(k1);
    khp[j] = h;
    klp[j] = f2b(k1 - b2f(h));
  }
  *(ushort4*)&q1h[i] = qh4;
  *(ushort4*)&q1l[i] = ql4;
  *(ushort4*)&k1h[i] = kh4;
  *(ushort4*)&k1l[i] = kl4;
}

// ---------- generic GEMM: C[M,N] = A[M,K] * B^T ----------
#define GM_BF16 0
#define GM_RELU 2
#define GM_ADDF32 3

template <int MODE>
__global__ __launch_bounds__(256, 3) void gemm_bt(const u16* __restrict__ A,
                                                  const u16* __restrict__ B, int M, int N, int K,
                                                  u16* __restrict__ outb, float* __restrict__ outf,
                                                  const float* __restrict__ res) {
  __shared__ u16 As[128 * 32];
  __shared__ u16 Bs[128 * 32];
  const int tid = threadIdx.x, lane = tid & 63, w = tid >> 6;
  const int wm = w >> 1, wn = w & 1;
  const long aBase = (long)blockIdx.x * 128;
  const long bBase = (long)blockIdx.y * 128;
  f32x4 acc[4][4] = {};
  const int nk = K >> 5;
  for (int kt = 0; kt < nk; ++kt) {
#pragma unroll
    for (int i = 0; i < 2; ++i) {
      const int c = w * 2 + i;
      const int off = c * 1024 + lane * 16;
      const int r = off >> 6, cb = off & 63;
      gload16((const char*)A + ((aBase + r) * (long)K + (long)kt * 32) * 2 + cb,
              (char*)As + c * 1024);
      gload16((const char*)B + ((bBase + r) * (long)K + (long)kt * 32) * 2 + cb,
              (char*)Bs + c * 1024);
    }
    __syncthreads();
    bf16x8 af[4], bfr[4];
#pragma unroll
    for (int x = 0; x < 4; ++x) {
      af[x] = *(const bf16x8*)&As[(wm * 64 + x * 16 + (lane & 15)) * 32 + (lane >> 4) * 8];
      bfr[x] = *(const bf16x8*)&Bs[(wn * 64 + x * 16 + (lane & 15)) * 32 + (lane >> 4) * 8];
    }
#pragma unroll
    for (int mf = 0; mf < 4; ++mf)
#pragma unroll
      for (int nf = 0; nf < 4; ++nf)
        acc[mf][nf] = MFMA(af[mf], bfr[nf], acc[mf][nf], 0, 0, 0);
    __syncthreads();
  }
#pragma unroll
  for (int mf = 0; mf < 4; ++mf)
#pragma unroll
    for (int nf = 0; nf < 4; ++nf) {
      const long row0 = aBase + wm * 64 + mf * 16 + (lane >> 4) * 4;
      const long col = bBase + wn * 64 + nf * 16 + (lane & 15);
#pragma unroll
      for (int j = 0; j < 4; ++j) {
        float v = acc[mf][nf][j];
        const long row = row0 + j;
        if constexpr (MODE == GM_BF16)
          outb[row * N + col] = f2b(v);
        else if constexpr (MODE == GM_RELU)
          outb[row * N + col] = f2b(v > 0.f ? v : 0.f);
        else
          outf[row * N + col] = res[row * N + col] + v;
      }
    }
}

// ---------- split-precision GEMM ----------
__global__ __launch_bounds__(256, 3) void gemm_split(const u16* __restrict__ Ah,
                                                     const u16* __restrict__ Al,
                                                     const u16* __restrict__ Bh,
                                                     const u16* __restrict__ Bl, int M, int N,
                                                     int K, u16* __restrict__ Oh,
                                                     u16* __restrict__ Ol) {
  __shared__ u16 Ash[4096], Asl[4096], Bsh[4096], Bsl[4096];
  const int tid = threadIdx.x, lane = tid & 63, w = tid >> 6;
  const int wm = w >> 1, wn = w & 1;
  const long aBase = (long)blockIdx.x * 128;
  const long bBase = (long)blockIdx.y * 128;
  f32x4 acc[4][4] = {};
  const int nk = K >> 5;
  for (int kt = 0; kt < nk; ++kt) {
#pragma unroll
    for (int i = 0; i < 2; ++i) {
      const int c = w * 2 + i;
      const int off = c * 1024 + lane * 16;
      const int r = off >> 6, cb = off & 63;
      long ga = ((aBase + r) * (long)K + (long)kt * 32) * 2 + cb;
      long gb = ((bBase + r) * (long)K + (long)kt * 32) * 2 + cb;
      gload16((const char*)Ah + ga, (char*)Ash + c * 1024);
      gload16((const char*)Al + ga, (char*)Asl + c * 1024);
      gload16((const char*)Bh + gb, (char*)Bsh + c * 1024);
      gload16((const char*)Bl + gb, (char*)Bsl + c * 1024);
    }
    __syncthreads();
    bf16x8 ah[4], al[4], bh[4], bl[4];
#pragma unroll
    for (int x = 0; x < 4; ++x) {
      int ao = (wm * 64 + x * 16 + (lane & 15)) * 32 + (lane >> 4) * 8;
      int bo = (wn * 64 + x * 16 + (lane & 15)) * 32 + (lane >> 4) * 8;
      ah[x] = *(const bf16x8*)&Ash[ao];
      al[x] = *(const bf16x8*)&Asl[ao];
      bh[x] = *(const bf16x8*)&Bsh[bo];
      bl[x] = *(const bf16x8*)&Bsl[bo];
    }
#pragma unroll
    for (int mf = 0; mf < 4; ++mf)
#pragma unroll
      for (int nf = 0; nf < 4; ++nf) {
        acc[mf][nf] = MFMA(ah[mf], bh[nf], acc[mf][nf], 0, 0, 0);
        acc[mf][nf] = MFMA(ah[mf], bl[nf], acc[mf][nf], 0, 0, 0);
        acc[mf][nf] = MFMA(al[mf], bh[nf], acc[mf][nf], 0, 0, 0);
      }
    __syncthreads();
  }
#pragma unroll
  for (int mf = 0; mf < 4; ++mf)
#pragma unroll
    for (int nf = 0; nf < 4; ++nf) {
      const long row0 = aBase + wm * 64 + mf * 16 + (lane >> 4) * 4;
      const long col = bBase + wn * 64 + nf * 16 + (lane & 15);
#pragma unroll
      for (int j = 0; j < 4; ++j) {
        float v = acc[mf][nf][j];
        const long row = row0 + j;
        u16 h = f2b(v);
        Oh[row * N + col] = h;
        Ol[row * N + col] = f2b(v - b2f(h));
      }
    }
}

// ---------- fused attention: one block per (h,b), 8 waves, K panel LDS-resident ----------
// Phase 1: colmax over q (LDS atomicMax). Phase 2: ONE K-sweep with all 4 q-subtiles —
// each K-fragment LDS read and each V global fetch shared by 4 states. Default 512-thread
// launch bounds -> 256-VGPR cap (LDS limits to 1 block/CU anyway; r13's (512,2) cap of 128
// caused the spill storm).
__global__ __launch_bounds__(512) void attn_fused(
    const u16* __restrict__ Qh, const u16* __restrict__ Ql, const u16* __restrict__ Kh,
    const u16* __restrict__ Kl, const u16* __restrict__ Vt, const int* __restrict__ qmask,
    const u16* __restrict__ r1h, const u16* __restrict__ r1l, float* __restrict__ resf,
    u16* __restrict__ resb) {
  extern __shared__ char smem[];
  u16* Khi = (u16*)smem;              // 8 chunks x [64][64] u16, swizzled (64 KB)
  u16* Klo = (u16*)(smem + 65536);    // 64 KB
  u32* mloc = (u32*)(smem + 131072);  // 512 x u32 (2 KB); later reused as float mks
  float* mksf = (float*)(smem + 131072);
  const int tid = threadIdx.x, lane = tid & 63, w = tid >> 6;
  const int qll = lane & 15, g = lane >> 4;
  const int hb = blockIdx.x, b = hb >> 3, h = hb & 7;
  const int qm = qmask[b];
  mloc[tid] = 0u;  // mapped sentinel below all mapped reals
  const int srccb = 16 * ((lane & 7) ^ ((lane >> 3) & 7));
  // stage full K panel (hi+lo), 8 chunks of 64 rows; linear LDS dest + inverse-swizzled source
#pragma unroll
  for (int c = 0; c < 8; ++c) {
    long gb = ((long)(b * 512 + c * 64 + w * 8 + (lane >> 3)) * 512 + h * 64) * 2 + srccb;
    gload16((const char*)Kh + gb, (char*)Khi + c * 8192 + w * 1024);
    gload16((const char*)Kl + gb, (char*)Klo + c * 8192 + w * 1024);
  }
  // Q fragments, all 4 subtiles of this wave (used in BOTH phases)
  bf16x8 qfh[4][2], qfl[4][2];
#pragma unroll
  for (int s = 0; s < 4; ++s) {
    const long qr = (long)(b * 512 + w * 64 + s * 16 + qll) * 512 + h * 64 + g * 8;
    qfh[s][0] = *(const bf16x8*)&Qh[qr];
    qfh[s][1] = *(const bf16x8*)&Qh[qr + 32];
    qfl[s][0] = *(const bf16x8*)&Ql[qr];
    qfl[s][1] = *(const bf16x8*)&Ql[qr + 32];
  }
  __syncthreads();  // K staged, mloc zeros visible
  const int sw0 = 8 * (g ^ (qll & 7));
  const int sw1 = 8 * ((4 + g) ^ (qll & 7));
  // ---- phase 1: column max over q ----
  for (int kc = 0; kc < 8; ++kc) {
    const int cb = kc * 4096;
    __builtin_amdgcn_s_setprio(1);
#pragma unroll
    for (int kt = 0; kt < 4; ++kt) {
      const int ko = cb + (kt * 16 + qll) * 64;
      bf16x8 kh0 = *(const bf16x8*)&Khi[ko + sw0];
      bf16x8 kl0 = *(const bf16x8*)&Klo[ko + sw0];
      bf16x8 kh1 = *(const bf16x8*)&Khi[ko + sw1];
      bf16x8 kl1 = *(const bf16x8*)&Klo[ko + sw1];
      float vmax = -3.0e38f;
#pragma unroll
      for (int s = 0; s < 4; ++s) {
        f32x4 acc = {0.f, 0.f, 0.f, 0.f};
        acc = MFMA(qfh[s][0], kh0, acc, 0, 0, 0);
        acc = MFMA(qfh[s][0], kl0, acc, 0, 0, 0);
        acc = MFMA(qfl[s][0], kh0, acc, 0, 0, 0);
        acc = MFMA(qfh[s][1], kh1, acc, 0, 0, 0);
        acc = MFMA(qfh[s][1], kl1, acc, 0, 0, 0);
        acc = MFMA(qfl[s][1], kh1, acc, 0, 0, 0);
        vmax = fmaxf(vmax, fmaxf(fmaxf(acc[0], acc[1]), fmaxf(acc[2], acc[3])));
      }
      vmax = fmaxf(vmax, __shfl_xor(vmax, 16));
      vmax = fmaxf(vmax, __shfl_xor(vmax, 32));
      if (lane < 16) atomicMax(&mloc[kc * 64 + kt * 16 + qll], mapf(vmax));
    }
    __builtin_amdgcn_s_setprio(0);
  }
  __syncthreads();
  float mv = 0.125f * unmapf(mloc[tid]);
  __syncthreads();
  mksf[tid] = mv;
  __syncthreads();
  // ---- phase 2: single K sweep, 4 states ----
  const u16* vb = Vt + (long)(h * 64) * 16384 + b * 512;
  const int src0 = (g & 1) * 32 + qll;
  const int src1 = src0 + 16;
  const bool lowh = g < 2;
  f32x4 o[4][4] = {};
  float mr[4] = {-3.0e38f, -3.0e38f, -3.0e38f, -3.0e38f};
  float rsum[4] = {0.f, 0.f, 0.f, 0.f};
  for (int kc = 0; kc < 8; ++kc) {
    // V fragments for this chunk (shared by all 4 states)
    bf16x8 vf[2][4];
#pragma unroll
    for (int k2 = 0; k2 < 2; ++k2)
#pragma unroll
      for (int nf = 0; nf < 4; ++nf)
        vf[k2][nf] =
            *(const bf16x8*)&vb[(long)(nf * 16 + qll) * 16384 + (kc * 2 + k2) * 32 + g * 8];
    // S^T tiles for all 4 states; K frags read ONCE per kt
    const int cb = kc * 4096;
    f32x4 s4[4][4] = {};  // [state][kt]
    __builtin_amdgcn_s_setprio(1);
#pragma unroll
    for (int kt = 0; kt < 4; ++kt) {
      const int ko = cb + (kt * 16 + qll) * 64;
      bf16x8 kh0 = *(const bf16x8*)&Khi[ko + sw0];
      bf16x8 kl0 = *(const bf16x8*)&Klo[ko + sw0];
      bf16x8 kh1 = *(const bf16x8*)&Khi[ko + sw1];
      bf16x8 kl1 = *(const bf16x8*)&Klo[ko + sw1];
#pragma unroll
      for (int s = 0; s < 4; ++s) {
        s4[s][kt] = MFMA(kh0, qfh[s][0], s4[s][kt], 0, 0, 0);
        s4[s][kt] = MFMA(kh0, qfl[s][0], s4[s][kt], 0, 0, 0);
        s4[s][kt] = MFMA(kl0, qfh[s][0], s4[s][kt], 0, 0, 0);
        s4[s][kt] = MFMA(kh1, qfh[s][1], s4[s][kt], 0, 0, 0);
        s4[s][kt] = MFMA(kh1, qfl[s][1], s4[s][kt], 0, 0, 0);
        s4[s][kt] = MFMA(kl1, qfh[s][1], s4[s][kt], 0, 0, 0);
      }
    }
    __builtin_amdgcn_s_setprio(0);
    // per state: z, running max, rescale, exp, pack, PV (identical math to round 9)
#pragma unroll
    for (int s = 0; s < 4; ++s) {
      float pm = mr[s];
#pragma unroll
      for (int kt = 0; kt < 4; ++kt) {
        f32x4 mrow = *(const f32x4*)&mksf[kc * 64 + kt * 16 + g * 4];
#pragma unroll
        for (int j = 0; j < 4; ++j) {
          float z = s4[s][kt][j] * 0.125f - mrow[j];
          s4[s][kt][j] = z;
          pm = fmaxf(pm, z);
        }
      }
      pm = fmaxf(pm, __shfl_xor(pm, 16));
      pm = fmaxf(pm, __shfl_xor(pm, 32));
      const float f = __expf(mr[s] - pm);
      mr[s] = pm;
      rsum[s] *= f;
#pragma unroll
      for (int nf = 0; nf < 4; ++nf) {
        o[s][nf][0] *= f;
        o[s][nf][1] *= f;
        o[s][nf][2] *= f;
        o[s][nf][3] *= f;
      }
      u32 pk0[4], pk1[4];
#pragma unroll
      for (int kt = 0; kt < 4; ++kt) {
        float p0 = __expf(s4[s][kt][0] - pm);
        float p1 = __expf(s4[s][kt][1] - pm);
        float p2 = __expf(s4[s][kt][2] - pm);
        float p3 = __expf(s4[s][kt][3] - pm);
        rsum[s] += (p0 + p1) + (p2 + p3);
        pk0[kt] = cvtpk(p0, p1);
        pk1[kt] = cvtpk(p2, p3);
      }
      __builtin_amdgcn_s_setprio(1);
#pragma unroll
      for (int k2 = 0; k2 < 2; ++k2) {
        const int fA = 2 * k2, fB = 2 * k2 + 1;
        u32 a00 = __shfl(pk0[fA], src0), b00 = __shfl(pk0[fB], src0);
        u32 a10 = __shfl(pk1[fA], src0), b10 = __shfl(pk1[fB], src0);
        u32 a01 = __shfl(pk0[fA], src1), b01 = __shfl(pk0[fB], src1);
        u32 a11 = __shfl(pk1[fA], src1), b11 = __shfl(pk1[fB], src1);
        union {
          u32 u[4];
          bf16x8 v;
        } pf;
        pf.u[0] = lowh ? a00 : b00;
        pf.u[1] = lowh ? a10 : b10;
        pf.u[2] = lowh ? a01 : b01;
        pf.u[3] = lowh ? a11 : b11;
#pragma unroll
        for (int nf = 0; nf < 4; ++nf) o[s][nf] = MFMA(vf[k2][nf], pf.v, o[s][nf], 0, 0, 0);
      }
      __builtin_amdgcn_s_setprio(0);
    }
  }
  // epilogue: all 4 states
#pragma unroll
  for (int s = 0; s < 4; ++s) {
    rsum[s] += __shfl_xor(rsum[s], 16);
    rsum[s] += __shfl_xor(rsum[s], 32);
    const int qg = w * 64 + s * 16 + qll;
    const float sc = (qg < qm) ? (1.0f / rsum[s]) : 0.0f;
#pragma unroll
    for (int nf = 0; nf < 4; ++nf) {
      const int col = h * 64 + nf * 16 + g * 4;
      const long idx = (long)(b * 512 + qg) * 512 + col;
      ushort4 qh4 = *(const ushort4*)&r1h[idx];
      ushort4 ql4 = *(const ushort4*)&r1l[idx];
      float v0 = o[s][nf][0] * sc + b2f(qh4.x) + b2f(ql4.x);
      float v1 = o[s][nf][1] * sc + b2f(qh4.y) + b2f(ql4.y);
      float v2 = o[s][nf][2] * sc + b2f(qh4.z) + b2f(ql4.z);
      float v3 = o[s][nf][3] * sc + b2f(qh4.w) + b2f(ql4.w);
      *(float4*)&resf[idx] = make_float4(v0, v1, v2, v3);
      ushort4 rb = {f2b(v0), f2b(v1), f2b(v2), f2b(v3)};
      *(ushort4*)&resb[idx] = rb;
    }
  }
}

// ---------- launch ----------
extern "C" void kernel_launch(void* const* d_in, const int* in_sizes, int n_in, void* d_out,
                              int out_size, void* d_ws, size_t ws_size, hipStream_t stream) {
  (void)in_sizes;
  (void)n_in;
  (void)out_size;
  (void)ws_size;
  const float* queries = (const float*)d_in[0];
  const int* qmask = (const int*)d_in[2];
  const float* WQ = (const float*)d_in[4];
  const float* WK = (const float*)d_in[5];
  const float* WV = (const float*)d_in[6];
  const float* f1 = (const float*)d_in[7];
  const float* f2 = (const float*)d_in[8];
  float* out = (float*)d_out;
  char* ws = (char*)d_ws;
  const size_t A = 16777216;
  u16* q1h = (u16*)(ws + 0 * A);
  u16* q1l = (u16*)(ws + 1 * A);
  u16* k1h = (u16*)(ws + 2 * A);
  u16* k1l = (u16*)(ws + 3 * A);
  u16* Qh = (u16*)(ws + 4 * A);
  u16* Ql = (u16*)(ws + 5 * A);
  u16* Kh = (u16*)(ws + 6 * A);
  u16* Kl = (u16*)(ws + 7 * A);
  u16* Vt = (u16*)(ws + 8 * A);
  u16* resb = (u16*)(ws + 9 * A);
  // hid (64 MiB) aliases slots 0-3; q1h/q1l last read by attn_fused (stream-ordered before FFN1)
  u16* hid = (u16*)(ws + 0 * A);
  float* pe = (float*)(ws + 10 * A);
  char* wbase = ws + 10 * A + 1572864;
  u16* WQth = (u16*)(wbase + 0 * 524288);
  u16* WQtl = (u16*)(wbase + 1 * 524288);
  u16* WKth = (u16*)(wbase + 2 * 524288);
  u16* WKtl = (u16*)(wbase + 3 * 524288);
  u16* WKb = (u16*)(wbase + 4 * 524288);
  u16* WVt_w = (u16*)(wbase + 5 * 524288);
  u16* WKVt = (u16*)(wbase + 6 * 524288);
  u16* f1t = (u16*)(wbase + 7 * 524288);
  u16* f2t = (u16*)(wbase + 7 * 524288 + 2097152);

  pe_kernel<<<1024, 256, 0, stream>>>(pe);
  wprep_kernel<<<960, 256, 0, stream>>>(WQ, WK, WV, f1, f2, WQth, WQtl, WKth, WKtl, WVt_w, f1t,
                                        f2t, WKb);
  prep_kernel<<<8192, 256, 0, stream>>>(queries, pe, q1h, q1l, k1h, k1l);
  // WKVt[v][n] = (WK@WV)^T : C = WVt_w * WKb^T
  gemm_bt<GM_BF16><<<dim3(4, 4), 256, 0, stream>>>(WVt_w, WKb, 512, 512, 512, WKVt, nullptr,
                                                   nullptr);
  gemm_split<<<dim3(128, 4), 256, 0, stream>>>(q1h, q1l, WQth, WQtl, 16384, 512, 512, Qh, Ql);
  gemm_split<<<dim3(128, 4), 256, 0, stream>>>(k1h, k1l, WKth, WKtl, 16384, 512, 512, Kh, Kl);
  // Vt[v][m] = V^T directly: C = WKVt * k1h^T
  gemm_bt<GM_BF16><<<dim3(4, 128), 256, 0, stream>>>(WKVt, k1h, 512, 16384, 512, Vt, nullptr,
                                                     nullptr);
  hipFuncSetAttribute((const void*)attn_fused, hipFuncAttributeMaxDynamicSharedMemorySize, 133120);
  attn_fused<<<256, 512, 133120, stream>>>(Qh, Ql, Kh, Kl, Vt, qmask, q1h, q1l, out, resb);
  gemm_bt<GM_RELU><<<dim3(128, 16), 256, 0, stream>>>(resb, f1t, 16384, 2048, 512, hid, nullptr,
                                                      nullptr);
  gemm_bt<GM_ADDF32><<<dim3(128, 4), 256, 0, stream>>>(hid, f2t, 16384, 512, 2048, nullptr, out,
                                                       out);
}